// Round 4
// baseline (702.488 us; speedup 1.0000x reference)
//
#include <hip/hip_runtime.h>

typedef unsigned short u16;
typedef unsigned int   u32;
typedef unsigned long long u64;
typedef float f2 __attribute__((ext_vector_type(2)));

#define CIN  20
#define DIN  32
#define BB   4
#define HH   384
#define WW   384
#define HW   147456
#define BHW  589824
#define EPSF 1e-5f
#define GUARD 65536

__device__ __forceinline__ float bflo(u32 u) {
    union { u32 v; float f; } x; x.v = u << 16; return x.f;
}
__device__ __forceinline__ float bfhi(u32 u) {
    union { u32 v; float f; } x; x.v = u & 0xffff0000u; return x.f;
}
__device__ __forceinline__ float bf2f(u16 h) {
    union { u32 v; float f; } x; x.v = ((u32)h) << 16; return x.f;
}
__device__ __forceinline__ u16 f2bf(float f) {
    union { float f; u32 u; } v; v.f = f;
    u32 u = v.u;
    return (u16)((u + 0x7FFFu + ((u >> 16) & 1u)) >> 16);
}
__device__ __forceinline__ u32 pk2(float a, float b) {
    return (u32)f2bf(a) | ((u32)f2bf(b) << 16);
}
__device__ __forceinline__ float silu_f(float a) {
    return a / (1.f + __expf(-a));
}
__device__ __forceinline__ float softplus_f(float z) {
    return (z > 15.f) ? z : __logf(1.f + __expf(z));
}

// ---------------- K0: fold merge+out weights ----------------
__global__ void k_prep(const float* __restrict__ ow, const float* __restrict__ mw,
                       const float* __restrict__ mg, const float* __restrict__ mb,
                       const float* __restrict__ ob,
                       float* __restrict__ Wt, float* __restrict__ rsum,
                       float* __restrict__ c0)
{
    __shared__ float mdot[DIN];
    int t = threadIdx.x; // 128 threads
    if (t < DIN) {
        float s = 0.f;
        for (int k = 0; k < 128; ++k) s += mw[t*128 + k] * mb[k];
        mdot[t] = s;
    }
    {
        int k = t;
        for (int o = 0; o < CIN; ++o) {
            float s = 0.f;
            for (int d = 0; d < DIN; ++d) s += ow[o*DIN + d] * mw[d*128 + k];
            Wt[k*CIN + o] = s * mg[k];
        }
    }
    __syncthreads();
    if (t < CIN) {
        float rs = 0.f;
        for (int k = 0; k < 128; ++k) rs += Wt[k*CIN + t];
        rsum[t] = rs;
        float c = ob[t];
        for (int d = 0; d < DIN; ++d) c += ow[t*DIN + d] * mdot[d];
        c0[t] = c;
    }
}

// ---------------- K1: fused LN + inproj + silu + dwconv3x3 + silu + proj ----------------
// Tile 16x16 pixels/block, 1-px halo of h1 (post-silu inproj output) in LDS.
// Emits: h2 (u, bf16x32/px), dl (bf16x4/px/dir), bc (B,C: fp32x16 if BIGBC else bf16x16).
template<bool BIGBC>
__global__ __launch_bounds__(256) void k_front(
    const float* __restrict__ x, const float* __restrict__ ng,
    const float* __restrict__ nb, const float* __restrict__ ipw,
    const float* __restrict__ cw, const float* __restrict__ cb,
    const float* __restrict__ xw,
    u16* __restrict__ h2, u16* __restrict__ dlA, char* __restrict__ bcA)
{
    __shared__ u32   h1_s[324*16];      // 18x18 halo tile, 32 bf16/px (20.25 KB)
    __shared__ float ipw_s[DIN*CIN];
    __shared__ float xw_s[4*CIN*DIN];
    __shared__ float cw_s[9*DIN];
    __shared__ float cb_s[DIN];
    __shared__ float g_s[CIN], b_s[CIN];

    int tid = threadIdx.x;
    for (int i = tid; i < DIN*CIN; i += 256) ipw_s[i] = ipw[i];
    for (int i = tid; i < 4*CIN*DIN; i += 256) xw_s[i] = xw[i];
    for (int i = tid; i < 9*DIN; i += 256) cw_s[i] = cw[i];
    if (tid < DIN) cb_s[tid] = cb[tid];
    if (tid < CIN) { g_s[tid] = ng[tid]; b_s[tid] = nb[tid]; }
    __syncthreads();

    int b  = blockIdx.z;
    int x0 = blockIdx.x*16 - 1, y0 = blockIdx.y*16 - 1;
    const float* xb = x + (size_t)b*CIN*HW;

    // Phase A: h1 for the 18x18 halo region
    for (int i = tid; i < 324; i += 256) {
        int hx = x0 + (i % 18), hy = y0 + (i / 18);
        u32* dst = &h1_s[i*16];
        if ((unsigned)hx >= 384u || (unsigned)hy >= 384u) {
            #pragma unroll
            for (int q = 0; q < 16; ++q) dst[q] = 0u;   // SAME zero-pad on h1
        } else {
            int pix = hy*WW + hx;
            float v[CIN]; float m = 0.f;
            #pragma unroll
            for (int c = 0; c < CIN; ++c) { v[c] = xb[c*HW + pix]; m += v[c]; }
            m *= (1.f/CIN);
            float var = 0.f;
            #pragma unroll
            for (int c = 0; c < CIN; ++c) { float dd = v[c]-m; var += dd*dd; }
            float rstd = rsqrtf(var*(1.f/CIN) + EPSF);
            #pragma unroll
            for (int c = 0; c < CIN; ++c) v[c] = (v[c]-m)*rstd*g_s[c] + b_s[c];
            #pragma unroll
            for (int q = 0; q < 16; ++q) {
                float a0 = 0.f, a1 = 0.f;
                #pragma unroll
                for (int c = 0; c < CIN; ++c) {
                    a0 += ipw_s[(2*q)*CIN + c]*v[c];
                    a1 += ipw_s[(2*q+1)*CIN + c]*v[c];
                }
                dst[q] = pk2(silu_f(a0), silu_f(a1));
            }
        }
    }
    __syncthreads();

    // Phase B: depthwise 3x3 from LDS
    int tx = tid & 15, ty = tid >> 4;
    float hc[DIN];
    #pragma unroll
    for (int i = 0; i < DIN; ++i) hc[i] = cb_s[i];
    #pragma unroll
    for (int ky = 0; ky < 3; ++ky) {
        #pragma unroll
        for (int kx = 0; kx < 3; ++kx) {
            const uint4* src = (const uint4*)&h1_s[((ty+ky)*18 + tx+kx)*16];
            const float* wp = &cw_s[(ky*3+kx)*DIN];
            #pragma unroll
            for (int q4 = 0; q4 < 4; ++q4) {
                uint4 w = src[q4];
                hc[q4*8+0] += wp[q4*8+0]*bflo(w.x); hc[q4*8+1] += wp[q4*8+1]*bfhi(w.x);
                hc[q4*8+2] += wp[q4*8+2]*bflo(w.y); hc[q4*8+3] += wp[q4*8+3]*bfhi(w.y);
                hc[q4*8+4] += wp[q4*8+4]*bflo(w.z); hc[q4*8+5] += wp[q4*8+5]*bfhi(w.z);
                hc[q4*8+6] += wp[q4*8+6]*bflo(w.w); hc[q4*8+7] += wp[q4*8+7]*bfhi(w.w);
            }
        }
    }
    #pragma unroll
    for (int i = 0; i < DIN; ++i) hc[i] = silu_f(hc[i]);

    int p = b*HW + (y0+1+ty)*WW + (x0+1+tx);

    // write h2 (u for scan)
    {
        u32 pk[16];
        #pragma unroll
        for (int q = 0; q < 16; ++q) pk[q] = pk2(hc[2*q], hc[2*q+1]);
        uint4* hd = (uint4*)(h2 + (size_t)p*DIN);
        hd[0] = make_uint4(pk[0], pk[1], pk[2], pk[3]);
        hd[1] = make_uint4(pk[4], pk[5], pk[6], pk[7]);
        hd[2] = make_uint4(pk[8], pk[9], pk[10],pk[11]);
        hd[3] = make_uint4(pk[12],pk[13],pk[14],pk[15]);
    }

    // Phase C: per-direction xdbl -> dl + (B,C)
    #pragma unroll 1
    for (int dir = 0; dir < 4; ++dir) {
        float xd[CIN];
        #pragma unroll
        for (int j = 0; j < CIN; ++j) xd[j] = 0.f;
        #pragma unroll
        for (int d4 = 0; d4 < 8; ++d4) {
            float u0 = hc[d4*4], u1 = hc[d4*4+1], u2 = hc[d4*4+2], u3 = hc[d4*4+3];
            #pragma unroll
            for (int j = 0; j < CIN; ++j) {
                float4 w4 = *(const float4*)&xw_s[(dir*CIN + j)*DIN + d4*4];
                xd[j] += w4.x*u0 + w4.y*u1 + w4.z*u2 + w4.w*u3;
            }
        }
        *(uint2*)(dlA + (size_t)(dir*BHW + p)*4) =
            make_uint2(pk2(xd[0], xd[1]), pk2(xd[2], xd[3]));
        if (BIGBC) {
            float4* bcd = (float4*)(bcA + (size_t)(dir*BHW + p)*64);
            bcd[0] = make_float4(xd[4],  xd[5],  xd[6],  xd[7]);
            bcd[1] = make_float4(xd[8],  xd[9],  xd[10], xd[11]);
            bcd[2] = make_float4(xd[12], xd[13], xd[14], xd[15]);
            bcd[3] = make_float4(xd[16], xd[17], xd[18], xd[19]);
        } else {
            uint4* bcd = (uint4*)(bcA + (size_t)(dir*BHW + p)*32);
            bcd[0] = make_uint4(pk2(xd[4],xd[5]),   pk2(xd[6],xd[7]),
                                pk2(xd[8],xd[9]),   pk2(xd[10],xd[11]));
            bcd[1] = make_uint4(pk2(xd[12],xd[13]), pk2(xd[14],xd[15]),
                                pk2(xd[16],xd[17]), pk2(xd[18],xd[19]));
        }
    }
}

// ---------------- K4: 4-direction selective scan ----------------
// lane = d (32 ch), 2 sequences/wave, 8 states/lane as 4x float2.
// Fast path: A_n = -(n+1) (validated on device) => a_n = r^(n+1), r = sigmoid(-z),
// dt = -log(r). BIGBC: B/C stored fp32 (no unpack).
template<bool BIGBC>
__global__ __launch_bounds__(256) void k_scan(
    const char* __restrict__ h2b,   // u data at +GUARD
    const char* __restrict__ dlb_,  // dl data at +GUARD (8B records)
    const char* __restrict__ bcb_,  // (B,C) data at +GUARD (64B fp32 or 32B bf16 records)
    const float* __restrict__ Alog, const float* __restrict__ Dp,
    const float* __restrict__ dwm,  const float* __restrict__ dbv,
    char* __restrict__ y4b)         // planar (dir, pixel, 32) bf16
{
    int tid  = blockIdx.x*256 + threadIdx.x;
    int wv   = tid >> 6, lane = tid & 63;
    int half = lane >> 5, d = lane & 31;
    int dir  = wv / 768;                 // uniform per wave
    int s    = (wv % 768)*2 + half;
    int b    = s / 384, r = s % 384;

    int p0, stp;
    if (dir == 0)      { p0 = b*HW + r*WW;           stp = 1;  }
    else if (dir == 1) { p0 = b*HW + r*WW + (WW-1);  stp = -1; }
    else if (dir == 2) { p0 = b*HW + r;              stp = WW; }
    else               { p0 = b*HW + (HH-1)*WW + r;  stp = -WW;}

    float Av[8];
    bool okl = true;
    #pragma unroll
    for (int j = 0; j < 8; ++j) {
        float e = __expf(Alog[(dir*DIN + d)*8 + j]);
        Av[j] = -e;
        okl = okl && (__builtin_fabsf(e - (float)(j+1)) < 2e-3f);
    }
    bool fast = (__ballot(okl) == ~0ull);

    float Dd  = Dp[dir*DIN + d];
    float dw0 = dwm[(dir*DIN + d)*4 + 0], dw1 = dwm[(dir*DIN + d)*4 + 1];
    float dw2 = dwm[(dir*DIN + d)*4 + 2], dw3 = dwm[(dir*DIN + d)*4 + 3];
    float dbc = dbv[dir*DIN + d];

    const int RSZ = BIGBC ? 64 : 32;
    u32 uo = GUARD + (u32)((p0*DIN + d)*2);            int su = stp*DIN*2;
    u32 yo = (u32)((dir*BHW + p0)*64 + d*2);           int sy = stp*64;
    u32 c1 = GUARD + (u32)((dir*BHW + p0)*8);          int s1 = stp*8;
    u32 c2 = GUARD + (u32)((dir*BHW + p0)*RSZ);        int s2 = stp*RSZ;

    u16 ub[2]; uint2 dlr[2];
    uint4  B4[2], C4[2];                  // small path
    float4 Ba[2], Bb[2], Ca[2], Cb[2];    // big path
    u32 fu = uo, f1 = c1, f2o = c2;

    auto fetch = [&](int sl) {
        ub[sl]  = *(const u16*)(h2b + fu);
        dlr[sl] = *(const uint2*)(dlb_ + f1);
        if (BIGBC) {
            Ba[sl] = *(const float4*)(bcb_ + f2o);
            Bb[sl] = *(const float4*)(bcb_ + f2o + 16);
            Ca[sl] = *(const float4*)(bcb_ + f2o + 32);
            Cb[sl] = *(const float4*)(bcb_ + f2o + 48);
        } else {
            B4[sl]  = *(const uint4*)(bcb_ + f2o);
            C4[sl]  = *(const uint4*)(bcb_ + f2o + 16);
        }
        fu += (u32)su; f1 += (u32)s1; f2o += (u32)s2;
    };

    fetch(0); fetch(1);

    f2 h0 = {0.f,0.f}, h1 = {0.f,0.f}, h2v = {0.f,0.f}, h3 = {0.f,0.f};

    #pragma unroll 2
    for (int t = 0; t < 384; ++t) {
        int sl = t & 1;
        float uu = bf2f(ub[sl]);
        uint2 dl = dlr[sl];
        f2 Bp0, Bp1, Bp2, Bp3, Cp0, Cp1, Cp2, Cp3;
        if (BIGBC) {
            float4 xa = Ba[sl], xb2 = Bb[sl], ya = Ca[sl], yb = Cb[sl];
            Bp0 = f2{xa.x, xa.y};  Bp1 = f2{xa.z, xa.w};
            Bp2 = f2{xb2.x, xb2.y}; Bp3 = f2{xb2.z, xb2.w};
            Cp0 = f2{ya.x, ya.y};  Cp1 = f2{ya.z, ya.w};
            Cp2 = f2{yb.x, yb.y};  Cp3 = f2{yb.z, yb.w};
        } else {
            uint4 Bv = B4[sl], Cv = C4[sl];
            Bp0 = f2{ bflo(Bv.x), bfhi(Bv.x) }; Bp1 = f2{ bflo(Bv.y), bfhi(Bv.y) };
            Bp2 = f2{ bflo(Bv.z), bfhi(Bv.z) }; Bp3 = f2{ bflo(Bv.w), bfhi(Bv.w) };
            Cp0 = f2{ bflo(Cv.x), bfhi(Cv.x) }; Cp1 = f2{ bflo(Cv.y), bfhi(Cv.y) };
            Cp2 = f2{ bflo(Cv.z), bfhi(Cv.z) }; Cp3 = f2{ bflo(Cv.w), bfhi(Cv.w) };
        }
        fetch(sl);   // loads for t+2

        float z = dbc + dw0*bflo(dl.x) + dw1*bfhi(dl.x)
                      + dw2*bflo(dl.y) + dw3*bfhi(dl.y);
        f2 a01, a23, a45, a67;
        float dt;
        if (fast) {
            z = fminf(z, 80.f);
            float rr = __builtin_amdgcn_rcpf(1.f + __expf(z)); // = exp(-dt)
            dt = -__logf(rr);
            float r2 = rr*rr;
            f2 rr2 = {r2, r2};
            a01 = f2{rr, r2};
            a23 = a01*rr2;
            a45 = a23*rr2;
            a67 = a45*rr2;
        } else {
            dt = softplus_f(z);
            f2 dt2 = {dt, dt};
            f2 e0 = dt2*f2{Av[0],Av[1]}, e1 = dt2*f2{Av[2],Av[3]};
            f2 e2 = dt2*f2{Av[4],Av[5]}, e3 = dt2*f2{Av[6],Av[7]};
            a01 = f2{ __expf(e0.x), __expf(e0.y) };
            a23 = f2{ __expf(e1.x), __expf(e1.y) };
            a45 = f2{ __expf(e2.x), __expf(e2.y) };
            a67 = f2{ __expf(e3.x), __expf(e3.y) };
        }

        float dtu = dt*uu;
        f2 du2 = {dtu, dtu};

        h0  = __builtin_elementwise_fma(a01, h0,  du2*Bp0);
        h1  = __builtin_elementwise_fma(a23, h1,  du2*Bp1);
        h2v = __builtin_elementwise_fma(a45, h2v, du2*Bp2);
        h3  = __builtin_elementwise_fma(a67, h3,  du2*Bp3);

        f2 yv = Cp0*h0;
        yv = __builtin_elementwise_fma(Cp1, h1,  yv);
        yv = __builtin_elementwise_fma(Cp2, h2v, yv);
        yv = __builtin_elementwise_fma(Cp3, h3,  yv);

        float y = yv.x + yv.y + Dd*uu;
        *(u16*)(y4b + yo) = f2bf(y);
        yo += (u32)sy;
    }
}

// ---------------- K5: LN(128) + folded 128->20 + NCHW transpose ----------------
__global__ __launch_bounds__(256) void k_merge(
    const u16* __restrict__ y4, const float* __restrict__ Wt,
    const float* __restrict__ rsum, const float* __restrict__ c0,
    float* __restrict__ out)
{
    __shared__ float Wt_s[128*CIN];
    __shared__ float rs_s[CIN], c0_s[CIN];
    for (int i = threadIdx.x; i < 128*CIN; i += 256) Wt_s[i] = Wt[i];
    if (threadIdx.x < CIN) { rs_s[threadIdx.x] = rsum[threadIdx.x]; c0_s[threadIdx.x] = c0[threadIdx.x]; }
    __syncthreads();

    int p = blockIdx.x*256 + threadIdx.x;
    int b = p / HW, rem = p % HW;

    float s1 = 0.f, s2 = 0.f;
    float acc[CIN];
    #pragma unroll
    for (int o = 0; o < CIN; ++o) acc[o] = 0.f;

    #pragma unroll 1
    for (int dirk = 0; dirk < 4; ++dirk) {
        const uint4* src = (const uint4*)(y4 + ((size_t)dirk*BHW + p)*32);
        #pragma unroll
        for (int q4 = 0; q4 < 4; ++q4) {
            uint4 v = src[q4];
            u32 w[4] = {v.x, v.y, v.z, v.w};
            #pragma unroll
            for (int i = 0; i < 4; ++i) {
                int k = dirk*32 + q4*8 + i*2;
                float a = bflo(w[i]); float c = bfhi(w[i]);
                s1 += a + c; s2 += a*a + c*c;
                const float4* w0 = (const float4*)&Wt_s[k*CIN];
                const float4* w1 = (const float4*)&Wt_s[(k+1)*CIN];
                #pragma unroll
                for (int o4 = 0; o4 < 5; ++o4) {
                    float4 x0 = w0[o4], x1 = w1[o4];
                    acc[o4*4+0] += x0.x*a + x1.x*c;
                    acc[o4*4+1] += x0.y*a + x1.y*c;
                    acc[o4*4+2] += x0.z*a + x1.z*c;
                    acc[o4*4+3] += x0.w*a + x1.w*c;
                }
            }
        }
    }
    float m = s1*(1.f/128.f);
    float var = s2*(1.f/128.f) - m*m;
    float rstd = rsqrtf(var + EPSF);
    #pragma unroll
    for (int o = 0; o < CIN; ++o) {
        float res = rstd*(acc[o] - m*rs_s[o]) + c0_s[o];
        out[(b*CIN + o)*HW + rem] = res;
    }
}

extern "C" void kernel_launch(void* const* d_in, const int* in_sizes, int n_in,
                              void* d_out, int out_size, void* d_ws, size_t ws_size,
                              hipStream_t stream)
{
    const float* x    = (const float*)d_in[0];
    const float* ng   = (const float*)d_in[1];
    const float* nb   = (const float*)d_in[2];
    const float* ipw  = (const float*)d_in[3];
    const float* cw   = (const float*)d_in[4];
    const float* cb   = (const float*)d_in[5];
    const float* xw   = (const float*)d_in[6];
    const float* dwm  = (const float*)d_in[7];
    const float* dbv  = (const float*)d_in[8];
    const float* Alog = (const float*)d_in[9];
    const float* Dpv  = (const float*)d_in[10];
    const float* mg   = (const float*)d_in[11];
    const float* mb   = (const float*)d_in[12];
    const float* mw   = (const float*)d_in[13];
    const float* ow   = (const float*)d_in[14];
    const float* ob   = (const float*)d_in[15];
    float* out = (float*)d_out;

    const size_t y4_bytes   = (size_t)4*BHW*DIN*2;   // 150,994,944 (planar)
    const size_t dl_bytes   = (size_t)4*BHW*8;       //  18,874,368
    const size_t bc16_bytes = (size_t)4*BHW*32;      //  75,497,472
    const size_t bc32_bytes = (size_t)4*BHW*64;      // 150,994,944
    const size_t wt_bytes   = (size_t)(128*CIN + 64)*4;

    char* ws = (char*)d_ws;
    u16* y4 = (u16*)ws;

    size_t dl_pos = y4_bytes + GUARD;
    size_t bc_pos = dl_pos + dl_bytes + GUARD;
    size_t need_small = bc_pos + bc16_bytes + GUARD + wt_bytes + GUARD; // ~245.8 MB (proven)
    size_t need_big   = bc_pos + bc32_bytes + GUARD + wt_bytes + GUARD; // ~321.7 MB

    if (ws_size < need_small) {
        hipMemsetAsync(d_out, 0x7F, (size_t)out_size*4, stream);  // diagnosable sentinel
        return;
    }
    bool big = (ws_size >= need_big);

    // h2 (u after conv) lives inside d_out with GUARD on both sides.
    char* h2base = (char*)d_out;                     // data at +GUARD
    u16*  h2 = (u16*)(h2base + GUARD);               // 37.75 MB + guards < 47.19 MB

    u16*  dlA = (u16*)(ws + dl_pos);
    char* bcA = ws + bc_pos;
    size_t wt_pos = bc_pos + (big ? bc32_bytes : bc16_bytes) + GUARD;
    float* Wt   = (float*)(ws + wt_pos);
    float* rsum = Wt + 128*CIN;
    float* c0   = rsum + 32;

    k_prep<<<1, 128, 0, stream>>>(ow, mw, mg, mb, ob, Wt, rsum, c0);

    dim3 fgrid(24, 24, 4);
    if (big) {
        k_front<true><<<fgrid, 256, 0, stream>>>(x, ng, nb, ipw, cw, cb, xw, h2, dlA, bcA);
        k_scan<true><<<768, 256, 0, stream>>>(
            h2base, (const char*)(ws + dl_pos - GUARD), (const char*)(ws + bc_pos - GUARD),
            Alog, Dpv, dwm, dbv, (char*)y4);
    } else {
        k_front<false><<<fgrid, 256, 0, stream>>>(x, ng, nb, ipw, cw, cb, xw, h2, dlA, bcA);
        k_scan<false><<<768, 256, 0, stream>>>(
            h2base, (const char*)(ws + dl_pos - GUARD), (const char*)(ws + bc_pos - GUARD),
            Alog, Dpv, dwm, dbv, (char*)y4);
    }

    k_merge<<<BHW/256, 256, 0, stream>>>(y4, Wt, rsum, c0, out);
}

// Round 5
// 559.799 us; speedup vs baseline: 1.2549x; 1.2549x over previous
//
#include <hip/hip_runtime.h>

typedef unsigned short u16;
typedef unsigned int   u32;
typedef unsigned long long u64;
typedef float f2 __attribute__((ext_vector_type(2)));
typedef __attribute__((ext_vector_type(8))) short s8v;   // 8 bf16 MFMA frag
typedef __attribute__((ext_vector_type(4))) float f4v;   // 4 f32 MFMA acc

#define CIN  20
#define DIN  32
#define BB   4
#define HH   384
#define WW   384
#define HW   147456
#define BHW  589824
#define EPSF 1e-5f
#define GUARD 65536

__device__ __forceinline__ float bflo(u32 u) {
    union { u32 v; float f; } x; x.v = u << 16; return x.f;
}
__device__ __forceinline__ float bfhi(u32 u) {
    union { u32 v; float f; } x; x.v = u & 0xffff0000u; return x.f;
}
__device__ __forceinline__ float bf2f(u16 h) {
    union { u32 v; float f; } x; x.v = ((u32)h) << 16; return x.f;
}
__device__ __forceinline__ u16 f2bf(float f) {
    union { float f; u32 u; } v; v.f = f;
    u32 u = v.u;
    return (u16)((u + 0x7FFFu + ((u >> 16) & 1u)) >> 16);
}
__device__ __forceinline__ u32 pk2(float a, float b) {
    return (u32)f2bf(a) | ((u32)f2bf(b) << 16);
}
__device__ __forceinline__ float silu_f(float a) {
    return a / (1.f + __expf(-a));
}
__device__ __forceinline__ float softplus_f(float z) {
    return (z > 15.f) ? z : __logf(1.f + __expf(z));
}

// ---------------- K0: fold merge+out weights + MFMA B-frag pack ----------------
// Wt[k][o] = merge_g[k] * sum_d out_w[o][d]*merge_w[d][k]   (128 x 20)
// Bfr[tile][dir][lane][j] = bf16(Wt[dir*32 + (lane>>4)*8 + j][tile*16 + (lane&15)])
__global__ void k_prep(const float* __restrict__ ow, const float* __restrict__ mw,
                       const float* __restrict__ mg, const float* __restrict__ mb,
                       const float* __restrict__ ob,
                       float* __restrict__ Wt, float* __restrict__ rsum,
                       float* __restrict__ c0, u16* __restrict__ Bfr)
{
    __shared__ float mdot[DIN];
    int t = threadIdx.x; // 128 threads
    if (t < DIN) {
        float s = 0.f;
        for (int k = 0; k < 128; ++k) s += mw[t*128 + k] * mb[k];
        mdot[t] = s;
    }
    {
        int k = t;
        for (int o = 0; o < CIN; ++o) {
            float s = 0.f;
            for (int d = 0; d < DIN; ++d) s += ow[o*DIN + d] * mw[d*128 + k];
            Wt[k*CIN + o] = s * mg[k];
        }
    }
    __syncthreads();
    if (t < CIN) {
        float rs = 0.f;
        for (int k = 0; k < 128; ++k) rs += Wt[k*CIN + t];
        rsum[t] = rs;
        float c = ob[t];
        for (int d = 0; d < DIN; ++d) c += ow[t*DIN + d] * mdot[d];
        c0[t] = c;
    }
    // B-frag pack (Wt already written & synced)
    for (int i = t; i < 4096; i += 128) {
        int j    = i & 7;
        int lane = (i >> 3) & 63;
        int dir  = (i >> 9) & 3;
        int tile = i >> 11;
        int o = tile*16 + (lane & 15);
        int k = dir*32 + ((lane >> 4) & 3)*8 + j;
        float v = (o < CIN) ? Wt[k*CIN + o] : 0.f;
        Bfr[i] = f2bf(v);
    }
}

// ---------------- K1: layernorm(C=20) + inproj(20->32) + silu ----------------
__global__ __launch_bounds__(256) void k_lnproj(
    const float* __restrict__ x, const float* __restrict__ ng,
    const float* __restrict__ nb, const float* __restrict__ ipw,
    u16* __restrict__ h1)
{
    __shared__ float w_s[DIN*CIN];
    __shared__ float g_s[CIN], b_s[CIN];
    for (int i = threadIdx.x; i < DIN*CIN; i += 256) w_s[i] = ipw[i];
    if (threadIdx.x < CIN) { g_s[threadIdx.x] = ng[threadIdx.x]; b_s[threadIdx.x] = nb[threadIdx.x]; }
    __syncthreads();

    int p = blockIdx.x*256 + threadIdx.x;
    int b = p / HW, rem = p % HW;
    float v[CIN];
    float m = 0.f;
    #pragma unroll
    for (int c = 0; c < CIN; ++c) { v[c] = x[(b*CIN + c)*HW + rem]; m += v[c]; }
    m *= (1.f/CIN);
    float var = 0.f;
    #pragma unroll
    for (int c = 0; c < CIN; ++c) { float d = v[c]-m; var += d*d; }
    var *= (1.f/CIN);
    float rstd = rsqrtf(var + EPSF);
    #pragma unroll
    for (int c = 0; c < CIN; ++c) v[c] = (v[c]-m)*rstd*g_s[c] + b_s[c];

    float o[DIN];
    #pragma unroll
    for (int j = 0; j < DIN; ++j) {
        float acc = 0.f;
        #pragma unroll
        for (int c = 0; c < CIN; ++c) acc += w_s[j*CIN + c]*v[c];
        o[j] = silu_f(acc);
    }
    u32 pk[16];
    #pragma unroll
    for (int j2 = 0; j2 < 16; ++j2)
        pk[j2] = pk2(o[2*j2], o[2*j2+1]);
    uint4* dst = (uint4*)(h1 + (size_t)p*DIN);
    dst[0] = make_uint4(pk[0],pk[1],pk[2],pk[3]);
    dst[1] = make_uint4(pk[4],pk[5],pk[6],pk[7]);
    dst[2] = make_uint4(pk[8],pk[9],pk[10],pk[11]);
    dst[3] = make_uint4(pk[12],pk[13],pk[14],pk[15]);
}

// ---------------- K2: depthwise 3x3 conv + bias + silu ----------------
__global__ __launch_bounds__(256) void k_conv(
    const u16* __restrict__ h1, const float* __restrict__ cw,
    const float* __restrict__ cb, u16* __restrict__ h2)
{
    __shared__ float w_s[9*DIN];
    __shared__ float b_s[DIN];
    for (int i = threadIdx.x; i < 9*DIN; i += 256) w_s[i] = cw[i];
    if (threadIdx.x < DIN) b_s[threadIdx.x] = cb[threadIdx.x];
    __syncthreads();

    int tid = blockIdx.x*256 + threadIdx.x;
    int p = tid >> 2, g = tid & 3;
    int b = p / HW, rem = p % HW;
    int yy0 = rem / WW, xx0 = rem % WW;

    float acc[8];
    #pragma unroll
    for (int i = 0; i < 8; ++i) acc[i] = b_s[g*8 + i];

    #pragma unroll
    for (int dy = -1; dy <= 1; ++dy) {
        int yy = yy0 + dy;
        #pragma unroll
        for (int dx = -1; dx <= 1; ++dx) {
            int xc = xx0 + dx;
            if (yy >= 0 && yy < HH && xc >= 0 && xc < WW) {
                uint4 q = *(const uint4*)(h1 + ((size_t)(b*HW + yy*WW + xc)*DIN + g*8));
                int k = (dy+1)*3 + (dx+1);
                const float* wp = &w_s[k*DIN + g*8];
                acc[0] += wp[0]*bflo(q.x);  acc[1] += wp[1]*bfhi(q.x);
                acc[2] += wp[2]*bflo(q.y);  acc[3] += wp[3]*bfhi(q.y);
                acc[4] += wp[4]*bflo(q.z);  acc[5] += wp[5]*bfhi(q.z);
                acc[6] += wp[6]*bflo(q.w);  acc[7] += wp[7]*bfhi(q.w);
            }
        }
    }
    u32 pk[4];
    #pragma unroll
    for (int i2 = 0; i2 < 4; ++i2) {
        float a = silu_f(acc[2*i2]);
        float c = silu_f(acc[2*i2+1]);
        pk[i2] = (u32)f2bf(a) | ((u32)f2bf(c) << 16);
    }
    *(uint4*)(h2 + ((size_t)p*DIN + g*8)) = make_uint4(pk[0],pk[1],pk[2],pk[3]);
}

// ---------------- K3: xdbl -> records ----------------
// COMB: one 48B record per (dir,px): [B 16B][C 16B][dl 8B][pad 8B]
// split: dl array (8B/rec) + bc array (32B/rec)  -- R3-proven fallback
template<bool COMB>
__global__ __launch_bounds__(256) void k_proj(
    const u16* __restrict__ h2, const float* __restrict__ xw,
    u16* __restrict__ dlA, u16* __restrict__ bcA)
{
    __shared__ float xw_s[4*CIN*DIN];
    for (int i = threadIdx.x; i < 4*CIN*DIN; i += 256) xw_s[i] = xw[i];
    __syncthreads();

    int p = blockIdx.x*256 + threadIdx.x;
    float u[DIN];
    const uint4* src = (const uint4*)(h2 + (size_t)p*DIN);
    #pragma unroll
    for (int q4 = 0; q4 < 4; ++q4) {
        uint4 v = src[q4];
        u[q4*8+0]=bflo(v.x); u[q4*8+1]=bfhi(v.x);
        u[q4*8+2]=bflo(v.y); u[q4*8+3]=bfhi(v.y);
        u[q4*8+4]=bflo(v.z); u[q4*8+5]=bfhi(v.z);
        u[q4*8+6]=bflo(v.w); u[q4*8+7]=bfhi(v.w);
    }
    #pragma unroll 1
    for (int dir = 0; dir < 4; ++dir) {
        float xd[CIN];
        #pragma unroll
        for (int j = 0; j < CIN; ++j) xd[j] = 0.f;
        #pragma unroll
        for (int d4 = 0; d4 < 8; ++d4) {
            float u0 = u[d4*4], u1 = u[d4*4+1], u2 = u[d4*4+2], u3 = u[d4*4+3];
            #pragma unroll
            for (int j = 0; j < CIN; ++j) {
                float4 w4 = *(const float4*)&xw_s[(dir*CIN + j)*DIN + d4*4];
                xd[j] += w4.x*u0 + w4.y*u1 + w4.z*u2 + w4.w*u3;
            }
        }
        u32 pk[10];
        #pragma unroll
        for (int i = 0; i < 10; ++i)
            pk[i] = pk2(xd[2*i], xd[2*i+1]);
        if (COMB) {
            u16* rp = dlA + (size_t)(dir*BHW + p)*24;   // 48B records
            *(uint4*)(rp)      = make_uint4(pk[2],pk[3],pk[4],pk[5]);   // B
            *(uint4*)(rp + 8)  = make_uint4(pk[6],pk[7],pk[8],pk[9]);   // C
            *(uint2*)(rp + 16) = make_uint2(pk[0], pk[1]);              // dl
        } else {
            *(uint2*)(dlA + (size_t)(dir*BHW + p)*4) = make_uint2(pk[0], pk[1]);
            uint4* bcd = (uint4*)(bcA + (size_t)(dir*BHW + p)*16);
            bcd[0] = make_uint4(pk[2], pk[3], pk[4], pk[5]);
            bcd[1] = make_uint4(pk[6], pk[7], pk[8], pk[9]);
        }
    }
}

// ---------------- K4: 4-direction selective scan ----------------
// lane = d (32 ch), 2 sequences/wave, 8 states/lane as 4x float2.
// Fast path (validated vs Alog on device): a_n = r^(n+1) with r = sigmoid(-z),
// dt = -log(r). COMB: single record stream (1 running address, imm offsets).
template<bool COMB>
__global__ __launch_bounds__(256) void k_scan(
    const char* __restrict__ h2b,   // u data at +GUARD
    const char* __restrict__ s1b,   // COMB: 48B records at +GUARD; split: dl at +GUARD
    const char* __restrict__ s2b,   // split only: bc at +GUARD
    const float* __restrict__ Alog, const float* __restrict__ Dp,
    const float* __restrict__ dwm,  const float* __restrict__ dbv,
    char* __restrict__ y4b)         // planar (dir, pixel, 32) bf16
{
    int tid  = blockIdx.x*256 + threadIdx.x;
    int wv   = tid >> 6, lane = tid & 63;
    int half = lane >> 5, d = lane & 31;
    int dir  = wv / 768;                 // uniform per wave
    int s    = (wv % 768)*2 + half;
    int b    = s / 384, r = s % 384;

    int p0, stp;
    if (dir == 0)      { p0 = b*HW + r*WW;           stp = 1;  }
    else if (dir == 1) { p0 = b*HW + r*WW + (WW-1);  stp = -1; }
    else if (dir == 2) { p0 = b*HW + r;              stp = WW; }
    else               { p0 = b*HW + (HH-1)*WW + r;  stp = -WW;}

    float Av[8];
    bool okl = true;
    #pragma unroll
    for (int j = 0; j < 8; ++j) {
        float e = __expf(Alog[(dir*DIN + d)*8 + j]);
        Av[j] = -e;
        okl = okl && (__builtin_fabsf(e - (float)(j+1)) < 2e-3f);
    }
    bool fast = (__ballot(okl) == ~0ull);

    float Dd  = Dp[dir*DIN + d];
    float dw0 = dwm[(dir*DIN + d)*4 + 0], dw1 = dwm[(dir*DIN + d)*4 + 1];
    float dw2 = dwm[(dir*DIN + d)*4 + 2], dw3 = dwm[(dir*DIN + d)*4 + 3];
    float dbc = dbv[dir*DIN + d];

    u32 uo = GUARD + (u32)((p0*DIN + d)*2);            int su = stp*DIN*2;
    u32 yo = (u32)((dir*BHW + p0)*64 + d*2);           int sy = stp*64;
    u32 c1, c2 = 0; int st1, st2 = 0;
    if (COMB) { c1 = GUARD + (u32)((dir*BHW + p0)*48); st1 = stp*48; }
    else {
        c1 = GUARD + (u32)((dir*BHW + p0)*8);          st1 = stp*8;
        c2 = GUARD + (u32)((dir*BHW + p0)*32);         st2 = stp*32;
    }

    u16 ub[2]; uint2 dlr[2]; uint4 B4[2], C4[2];
    u32 fu = uo, f1 = c1, f2o = c2;

    auto fetch = [&](int sl) {
        ub[sl]  = *(const u16*)(h2b + fu);
        if (COMB) {
            B4[sl]  = *(const uint4*)(s1b + f1);
            C4[sl]  = *(const uint4*)(s1b + f1 + 16);
            dlr[sl] = *(const uint2*)(s1b + f1 + 32);
        } else {
            dlr[sl] = *(const uint2*)(s1b + f1);
            B4[sl]  = *(const uint4*)(s2b + f2o);
            C4[sl]  = *(const uint4*)(s2b + f2o + 16);
            f2o += (u32)st2;
        }
        fu += (u32)su; f1 += (u32)st1;
    };

    fetch(0); fetch(1);

    f2 h0 = {0.f,0.f}, h1 = {0.f,0.f}, h2v = {0.f,0.f}, h3 = {0.f,0.f};

    #pragma unroll 2
    for (int t = 0; t < 384; ++t) {
        int sl = t & 1;
        float uu = bf2f(ub[sl]);
        uint2 dl = dlr[sl];
        uint4 Bv = B4[sl], Cv = C4[sl];
        fetch(sl);   // loads for t+2

        float z = dbc + dw0*bflo(dl.x) + dw1*bfhi(dl.x)
                      + dw2*bflo(dl.y) + dw3*bfhi(dl.y);
        f2 a01, a23, a45, a67;
        float dt;
        if (fast) {
            z = fminf(z, 80.f);
            float rr = __builtin_amdgcn_rcpf(1.f + __expf(z)); // = exp(-dt)
            dt = -__logf(rr);
            float r2 = rr*rr;
            f2 rr2 = {r2, r2};
            a01 = f2{rr, r2};
            a23 = a01*rr2;
            a45 = a23*rr2;
            a67 = a45*rr2;
        } else {
            dt = softplus_f(z);
            f2 dt2 = {dt, dt};
            f2 e0 = dt2*f2{Av[0],Av[1]}, e1 = dt2*f2{Av[2],Av[3]};
            f2 e2 = dt2*f2{Av[4],Av[5]}, e3 = dt2*f2{Av[6],Av[7]};
            a01 = f2{ __expf(e0.x), __expf(e0.y) };
            a23 = f2{ __expf(e1.x), __expf(e1.y) };
            a45 = f2{ __expf(e2.x), __expf(e2.y) };
            a67 = f2{ __expf(e3.x), __expf(e3.y) };
        }

        f2 Bp0 = f2{ bflo(Bv.x), bfhi(Bv.x) }, Bp1 = f2{ bflo(Bv.y), bfhi(Bv.y) };
        f2 Bp2 = f2{ bflo(Bv.z), bfhi(Bv.z) }, Bp3 = f2{ bflo(Bv.w), bfhi(Bv.w) };
        f2 Cp0 = f2{ bflo(Cv.x), bfhi(Cv.x) }, Cp1 = f2{ bflo(Cv.y), bfhi(Cv.y) };
        f2 Cp2 = f2{ bflo(Cv.z), bfhi(Cv.z) }, Cp3 = f2{ bflo(Cv.w), bfhi(Cv.w) };

        float dtu = dt*uu;
        f2 du2 = {dtu, dtu};

        h0  = __builtin_elementwise_fma(a01, h0,  du2*Bp0);
        h1  = __builtin_elementwise_fma(a23, h1,  du2*Bp1);
        h2v = __builtin_elementwise_fma(a45, h2v, du2*Bp2);
        h3  = __builtin_elementwise_fma(a67, h3,  du2*Bp3);

        f2 yv = Cp0*h0;
        yv = __builtin_elementwise_fma(Cp1, h1,  yv);
        yv = __builtin_elementwise_fma(Cp2, h2v, yv);
        yv = __builtin_elementwise_fma(Cp3, h3,  yv);

        float y = yv.x + yv.y + Dd*uu;
        *(u16*)(y4b + yo) = f2bf(y);
        yo += (u32)sy;
    }
}

// ---------------- K5: MFMA LN(128)+128->20 merge + NCHW transpose ----------------
// Per wave: 4 tiles of 16 px. A-frag: y4[dir][px=lane&15][quad*8+j] (16B load).
// D = A * Wt_bf16 via 8x mfma_f32_16x16x32_bf16 (2 n-tiles x 4 dir K-blocks).
// LN folded: out = rstd*(acc - mu*rsum) + c0 applied per element in epilogue.
__global__ __launch_bounds__(256) void k_merge_m(
    const u16* __restrict__ y4, const u16* __restrict__ bfr,
    const float* __restrict__ rsum, const float* __restrict__ c0,
    float* __restrict__ out)
{
    int w = threadIdx.x >> 6, lane = threadIdx.x & 63;
    int quad = lane >> 4, mcol = lane & 15;

    s8v bf[2][4];
    #pragma unroll
    for (int tile = 0; tile < 2; ++tile)
        #pragma unroll
        for (int dir = 0; dir < 4; ++dir)
            bf[tile][dir] = *(const s8v*)(bfr + ((size_t)((tile*4+dir)*64 + lane))*8);

    int o0 = mcol, o1 = 16 + mcol;
    float rs0 = rsum[o0], cc0 = c0[o0];
    float rs1 = (o1 < CIN) ? rsum[o1] : 0.f;
    float cc1 = (o1 < CIN) ? c0[o1] : 0.f;

    int pxblock = blockIdx.x*256 + w*64;
    int b = pxblock / HW, rem0 = pxblock % HW;

    #pragma unroll 1
    for (int tt = 0; tt < 4; ++tt) {
        int px = pxblock + tt*16 + mcol;
        uint4 aw[4]; s8v af[4];
        f2 s1v = {0.f,0.f}, s2v = {0.f,0.f};
        #pragma unroll
        for (int dir = 0; dir < 4; ++dir) {
            aw[dir] = *(const uint4*)(y4 + ((size_t)dir*BHW + px)*32 + quad*8);
            af[dir] = __builtin_bit_cast(s8v, aw[dir]);
            u32 ww[4] = {aw[dir].x, aw[dir].y, aw[dir].z, aw[dir].w};
            #pragma unroll
            for (int i = 0; i < 4; ++i) {
                f2 v = { bflo(ww[i]), bfhi(ww[i]) };
                s1v = s1v + v;
                s2v = __builtin_elementwise_fma(v, v, s2v);
            }
        }
        float s1 = s1v.x + s1v.y, s2 = s2v.x + s2v.y;
        s1 += __shfl_xor(s1, 16, 64); s2 += __shfl_xor(s2, 16, 64);
        s1 += __shfl_xor(s1, 32, 64); s2 += __shfl_xor(s2, 32, 64);
        float mu   = s1*(1.f/128.f);
        float var  = s2*(1.f/128.f) - mu*mu;
        float rstd = rsqrtf(var + EPSF);

        f4v acc0 = {0.f,0.f,0.f,0.f}, acc1 = {0.f,0.f,0.f,0.f};
        #pragma unroll
        for (int dir = 0; dir < 4; ++dir) {
            acc0 = __builtin_amdgcn_mfma_f32_16x16x32_bf16(af[dir], bf[0][dir], acc0, 0, 0, 0);
            acc1 = __builtin_amdgcn_mfma_f32_16x16x32_bf16(af[dir], bf[1][dir], acc1, 0, 0, 0);
        }

        float mur[4], rsr[4];
        #pragma unroll
        for (int rg = 0; rg < 4; ++rg) {
            int row = quad*4 + rg;
            mur[rg] = __shfl(mu,   row, 64);
            rsr[rg] = __shfl(rstd, row, 64);
        }
        int rembase = rem0 + tt*16 + quad*4;
        {
            float4 o4;
            o4.x = rsr[0]*(acc0.x - mur[0]*rs0) + cc0;
            o4.y = rsr[1]*(acc0.y - mur[1]*rs0) + cc0;
            o4.z = rsr[2]*(acc0.z - mur[2]*rs0) + cc0;
            o4.w = rsr[3]*(acc0.w - mur[3]*rs0) + cc0;
            *(float4*)(out + (size_t)(b*CIN + o0)*HW + rembase) = o4;
        }
        if (o1 < CIN) {
            float4 o4;
            o4.x = rsr[0]*(acc1.x - mur[0]*rs1) + cc1;
            o4.y = rsr[1]*(acc1.y - mur[1]*rs1) + cc1;
            o4.z = rsr[2]*(acc1.z - mur[2]*rs1) + cc1;
            o4.w = rsr[3]*(acc1.w - mur[3]*rs1) + cc1;
            *(float4*)(out + (size_t)(b*CIN + o1)*HW + rembase) = o4;
        }
    }
}

extern "C" void kernel_launch(void* const* d_in, const int* in_sizes, int n_in,
                              void* d_out, int out_size, void* d_ws, size_t ws_size,
                              hipStream_t stream)
{
    const float* x    = (const float*)d_in[0];
    const float* ng   = (const float*)d_in[1];
    const float* nb   = (const float*)d_in[2];
    const float* ipw  = (const float*)d_in[3];
    const float* cw   = (const float*)d_in[4];
    const float* cb   = (const float*)d_in[5];
    const float* xw   = (const float*)d_in[6];
    const float* dwm  = (const float*)d_in[7];
    const float* dbv  = (const float*)d_in[8];
    const float* Alog = (const float*)d_in[9];
    const float* Dpv  = (const float*)d_in[10];
    const float* mg   = (const float*)d_in[11];
    const float* mb   = (const float*)d_in[12];
    const float* mw   = (const float*)d_in[13];
    const float* ow   = (const float*)d_in[14];
    const float* ob   = (const float*)d_in[15];
    float* out = (float*)d_out;

    const size_t y4_bytes  = (size_t)4*BHW*DIN*2;    // 150,994,944 (planar)
    const size_t dl_bytes  = (size_t)4*BHW*8;        //  18,874,368
    const size_t bc_bytes  = (size_t)4*BHW*32;       //  75,497,472
    const size_t rec_bytes = (size_t)4*BHW*48;       // 113,246,208
    const size_t wt_bytes  = 10240 + 256 + 8192;     // Wt + rsum/c0 + Bfrag

    char* ws = (char*)d_ws;
    u16* y4 = (u16*)ws;
    u16* h1 = y4;                                    // alias: h1 dead before y4 written

    size_t s1_pos = y4_bytes + GUARD;
    // split layout (R3-proven ~245.7 MB)
    size_t bc_pos       = s1_pos + dl_bytes + GUARD;
    size_t wt_pos_split = bc_pos + bc_bytes + GUARD;
    size_t need_split   = wt_pos_split + wt_bytes + GUARD;
    // combined layout (~264.5 MB)
    size_t wt_pos_comb  = s1_pos + rec_bytes + GUARD;
    size_t need_comb    = wt_pos_comb + wt_bytes + GUARD;

    if (ws_size < need_split) {
        hipMemsetAsync(d_out, 0x7F, (size_t)out_size*4, stream);  // diagnosable sentinel
        return;
    }
    bool comb = (ws_size >= need_comb);

    // h2 (u after conv) lives inside d_out with GUARD on both sides.
    char* h2base = (char*)d_out;                     // data at +GUARD
    u16*  h2 = (u16*)(h2base + GUARD);               // 37.75 MB + guards < 47.19 MB

    size_t wt_pos = comb ? wt_pos_comb : wt_pos_split;
    float* Wt   = (float*)(ws + wt_pos);
    float* rsum = Wt + 128*CIN;
    float* c0   = rsum + 32;
    u16*   Bfr  = (u16*)(ws + wt_pos + 10240 + 256);

    k_prep  <<<1, 128, 0, stream>>>(ow, mw, mg, mb, ob, Wt, rsum, c0, Bfr);
    k_lnproj<<<BHW/256, 256, 0, stream>>>(x, ng, nb, ipw, h1);
    k_conv  <<<BHW*4/256, 256, 0, stream>>>(h1, cw, cb, h2);

    if (comb) {
        u16* rec = (u16*)(ws + s1_pos);
        k_proj<true><<<BHW/256, 256, 0, stream>>>(h2, xw, rec, nullptr);
        k_scan<true><<<768, 256, 0, stream>>>(
            h2base, (const char*)(ws + s1_pos - GUARD), nullptr,
            Alog, Dpv, dwm, dbv, (char*)y4);
    } else {
        u16* dlA = (u16*)(ws + s1_pos);
        u16* bcA = (u16*)(ws + bc_pos);
        k_proj<false><<<BHW/256, 256, 0, stream>>>(h2, xw, dlA, bcA);
        k_scan<false><<<768, 256, 0, stream>>>(
            h2base, (const char*)(ws + s1_pos - GUARD), (const char*)(ws + bc_pos - GUARD),
            Alog, Dpv, dwm, dbv, (char*)y4);
    }

    k_merge_m<<<BHW/256, 256, 0, stream>>>(y4, Bfr, rsum, c0, out);
}